// Round 2
// baseline (631.850 us; speedup 1.0000x reference)
//
#include <hip/hip_runtime.h>

#define IN_SIZE 256
#define HIDDEN 16
#define OUT_SIZE 64
#define SCAN_BLK 1024  // elements scanned per block (256 thr x 4)

// ---------------- zero ----------------
__global__ __launch_bounds__(256) void zero_kernel(float* __restrict__ a, long n) {
    long i = (long)blockIdx.x * blockDim.x + threadIdx.x;
    long stride = (long)gridDim.x * blockDim.x;
    for (; i < n; i += stride) a[i] = 0.0f;
}

// ---------------- H1 = X @ W1^T + b1  [n,16] ----------------
__global__ __launch_bounds__(256) void dense1_kernel(
    const float* __restrict__ X, const float* __restrict__ W1,
    const float* __restrict__ b1, float* __restrict__ H1, int n) {
    __shared__ float w[HIDDEN * IN_SIZE];  // w[k*16 + h] = W1[h][k]
    for (int i = threadIdx.x; i < HIDDEN * IN_SIZE; i += 256) {
        int h = i >> 8;
        int k = i & 255;
        w[k * HIDDEN + h] = W1[i];
    }
    __syncthreads();
    int t = threadIdx.x;
    int node = blockIdx.x * 16 + (t >> 4);
    int h = t & 15;
    if (node >= n) return;
    const float4* xr = reinterpret_cast<const float4*>(X + (size_t)node * IN_SIZE);
    float acc = b1[h];
#pragma unroll 8
    for (int kk = 0; kk < IN_SIZE / 4; ++kk) {
        float4 x = xr[kk];
        const float* wr = &w[(kk * 4) * HIDDEN + h];
        acc += x.x * wr[0 * HIDDEN] + x.y * wr[1 * HIDDEN] +
               x.z * wr[2 * HIDDEN] + x.w * wr[3 * HIDDEN];
    }
    H1[(size_t)node * HIDDEN + h] = acc;
}

// ---------------- CSR build ----------------
__global__ __launch_bounds__(256) void hist_kernel(
    const int* __restrict__ row, int* __restrict__ cnt, long nedges) {
    long e = (long)blockIdx.x * 256 + threadIdx.x;
    if (e < nedges) atomicAdd(&cnt[row[e]], 1);
}

__global__ __launch_bounds__(256) void scan_blocks_kernel(
    const int* __restrict__ cnt, int* __restrict__ out, int* __restrict__ bsum, int n) {
    __shared__ int s[256];
    int base = blockIdx.x * SCAN_BLK;
    int tid = threadIdx.x;
    int v[4];
    int sum = 0;
#pragma unroll
    for (int j = 0; j < 4; ++j) {
        int i = base + tid * 4 + j;
        v[j] = (i < n) ? cnt[i] : 0;
        sum += v[j];
    }
    s[tid] = sum;
    __syncthreads();
    for (int off = 1; off < 256; off <<= 1) {
        int t = (tid >= off) ? s[tid - off] : 0;
        __syncthreads();
        s[tid] += t;
        __syncthreads();
    }
    int run = s[tid] - sum;  // exclusive prefix of this thread's chunk
    if (tid == 255) bsum[blockIdx.x] = s[255];
#pragma unroll
    for (int j = 0; j < 4; ++j) {
        int i = base + tid * 4 + j;
        if (i < n) out[i] = run;
        run += v[j];
    }
}

__global__ __launch_bounds__(256) void scan_top_kernel(int* __restrict__ bsum, int nb) {
    __shared__ int s[256];
    int tid = threadIdx.x;
    int x = (tid < nb) ? bsum[tid] : 0;
    s[tid] = x;
    __syncthreads();
    for (int off = 1; off < 256; off <<= 1) {
        int t = (tid >= off) ? s[tid - off] : 0;
        __syncthreads();
        s[tid] += t;
        __syncthreads();
    }
    if (tid < nb) bsum[tid] = s[tid] - x;  // exclusive
}

__global__ __launch_bounds__(256) void scan_add_kernel(
    int* __restrict__ row_ptr, int* __restrict__ cursor,
    const int* __restrict__ bsum, int n, int nedges) {
    int i = blockIdx.x * 256 + threadIdx.x;
    if (i < n) {
        int v = row_ptr[i] + bsum[i / SCAN_BLK];
        row_ptr[i] = v;
        cursor[i] = v;
    }
    if (i == n) row_ptr[n] = nedges;
}

__global__ __launch_bounds__(256) void scatter_kernel(
    const int* __restrict__ row, const int* __restrict__ col,
    const float* __restrict__ val, int* __restrict__ cursor,
    float2* __restrict__ epack, long nedges) {
    long e = (long)blockIdx.x * 256 + threadIdx.x;
    if (e >= nedges) return;
    int r = row[e];
    int p = atomicAdd(&cursor[r], 1);
    epack[p] = make_float2(__int_as_float(col[e]), val[e]);
}

// ---------------- pull spmm: Sout[r] = sum val*(relu?)(Hin[c]), deg[r] ----------------
// 4 lanes per row, each lane owns 4 features via float4.
__global__ __launch_bounds__(256) void spmm_pull_kernel(
    const int* __restrict__ row_ptr, const float2* __restrict__ epack,
    const float* __restrict__ Hin, float* __restrict__ Sout,
    float* __restrict__ deg, int n, int relu_in) {
    int t = blockIdx.x * 256 + threadIdx.x;
    int r = t >> 2;
    int q = t & 3;
    if (r >= n) return;
    int e0 = row_ptr[r], e1 = row_ptr[r + 1];
    float4 acc = make_float4(0.f, 0.f, 0.f, 0.f);
    float d = 0.f;
    for (int e = e0; e < e1; ++e) {
        float2 p = epack[e];            // 4 lanes broadcast same 8B
        int c = __float_as_int(p.x);
        float v = p.y;
        float4 x = reinterpret_cast<const float4*>(Hin + (size_t)c * HIDDEN)[q];
        if (relu_in) {
            x.x = fmaxf(x.x, 0.f); x.y = fmaxf(x.y, 0.f);
            x.z = fmaxf(x.z, 0.f); x.w = fmaxf(x.w, 0.f);
        }
        acc.x += v * x.x; acc.y += v * x.y;
        acc.z += v * x.z; acc.w += v * x.w;
        d += v;
    }
    reinterpret_cast<float4*>(Sout + (size_t)r * HIDDEN)[q] = acc;
    if (deg != nullptr && q == 0) deg[r] = d;
}

// ---------------- legacy atomic spmm (fallback if ws too small) ----------------
__global__ __launch_bounds__(256) void spmm16_kernel(
    const int* __restrict__ row, const int* __restrict__ col,
    const float* __restrict__ val, const float* __restrict__ Hin,
    float* __restrict__ Sout, float* __restrict__ deg, long nedges, int relu_in) {
    long t = (long)blockIdx.x * 256 + threadIdx.x;
    long e = t >> 4;
    if (e >= nedges) return;
    int k = (int)(t & 15);
    int r = row[e];
    int c = col[e];
    float v = val[e];
    float x = Hin[(size_t)c * HIDDEN + k];
    if (relu_in) x = fmaxf(x, 0.0f);
    atomicAdd(&Sout[(size_t)r * HIDDEN + k], v * x);
    if (deg != nullptr && k == 0) atomicAdd(&deg[r], v);
}

// ---------------- out = relu(T @ W2^T + deg*b2)  [n,64] ----------------
__global__ __launch_bounds__(256) void dense2_kernel(
    const float* __restrict__ T, const float* __restrict__ deg,
    const float* __restrict__ W2, const float* __restrict__ b2,
    float* __restrict__ out, int n) {
    __shared__ float w[OUT_SIZE * HIDDEN];  // w[h*64 + o] = W2[o][h]
    for (int i = threadIdx.x; i < OUT_SIZE * HIDDEN; i += 256) {
        int o = i / HIDDEN;
        int h = i % HIDDEN;
        w[h * OUT_SIZE + o] = W2[i];
    }
    __syncthreads();
    int node = blockIdx.x * 4 + (threadIdx.x >> 6);
    int o = threadIdx.x & 63;
    if (node >= n) return;
    float acc = deg[node] * b2[o];
#pragma unroll
    for (int h = 0; h < HIDDEN; ++h)
        acc += T[(size_t)node * HIDDEN + h] * w[h * OUT_SIZE + o];
    out[(size_t)node * OUT_SIZE + o] = fmaxf(acc, 0.0f);
}

extern "C" void kernel_launch(void* const* d_in, const int* in_sizes, int n_in,
                              void* d_out, int out_size, void* d_ws, size_t ws_size,
                              hipStream_t stream) {
    const int*   index = (const int*)d_in[0];
    const float* value = (const float*)d_in[1];
    const float* X     = (const float*)d_in[4];
    const float* W1    = (const float*)d_in[5];
    const float* b1    = (const float*)d_in[6];
    const float* W2    = (const float*)d_in[7];
    const float* b2    = (const float*)d_in[8];
    float* out = (float*)d_out;

    long nedges = in_sizes[1];
    int  n      = in_sizes[4] / IN_SIZE;
    const int* row = index;
    const int* col = index + nedges;

    // --- CSR-path workspace layout ---
    // epack[nedges] f2 | cnt[n] | row_ptr[n+1] | cursor[n] | bsum[256] |
    // H1[n*16] (reused as T) | S1[n*16] | deg[n]
    size_t need = (size_t)nedges * 8 + ((size_t)3 * n + 1 + 256) * 4 +
                  ((size_t)n * 2 * HIDDEN + n) * 4 + 256;

    if (ws_size >= need) {
        float2* epack  = (float2*)d_ws;
        int* cnt       = (int*)(epack + nedges);
        int* row_ptr   = cnt + n;
        int* cursor    = row_ptr + (n + 1);
        int* bsum      = cursor + n;
        float* H1      = (float*)(bsum + 256);   // also T
        float* S1      = H1 + (size_t)n * HIDDEN;
        float* deg     = S1 + (size_t)n * HIDDEN;

        int eblocks = (int)((nedges + 255) / 256);
        int nb = (n + SCAN_BLK - 1) / SCAN_BLK;  // <= 256 for n <= 262144

        zero_kernel<<<256, 256, 0, stream>>>((float*)cnt, n);
        hist_kernel<<<eblocks, 256, 0, stream>>>(row, cnt, nedges);
        scan_blocks_kernel<<<nb, 256, 0, stream>>>(cnt, row_ptr, bsum, n);
        scan_top_kernel<<<1, 256, 0, stream>>>(bsum, nb);
        scan_add_kernel<<<(n + 256) / 256, 256, 0, stream>>>(row_ptr, cursor, bsum, n, (int)nedges);
        scatter_kernel<<<eblocks, 256, 0, stream>>>(row, col, value, cursor, epack, nedges);

        dense1_kernel<<<(n + 15) / 16, 256, 0, stream>>>(X, W1, b1, H1, n);

        int sblocks = ((n * 4) + 255) / 256;
        spmm_pull_kernel<<<sblocks, 256, 0, stream>>>(row_ptr, epack, H1, S1, deg, n, 0);
        float* T = H1;  // reuse
        spmm_pull_kernel<<<sblocks, 256, 0, stream>>>(row_ptr, epack, S1, T, nullptr, n, 1);

        dense2_kernel<<<(n + 3) / 4, 256, 0, stream>>>(T, deg, W2, b2, out, n);
    } else {
        // fallback: atomic push path (round-1 behavior)
        float* ws = (float*)d_ws;
        float* H1  = ws;
        float* S1  = H1 + (size_t)n * HIDDEN;
        float* T   = S1 + (size_t)n * HIDDEN;
        float* deg = T + (size_t)n * HIDDEN;
        zero_kernel<<<2048, 256, 0, stream>>>(S1, (long)n * (2 * HIDDEN + 1));
        dense1_kernel<<<(n + 15) / 16, 256, 0, stream>>>(X, W1, b1, H1, n);
        long thr1 = nedges * HIDDEN;
        spmm16_kernel<<<(int)((thr1 + 255) / 256), 256, 0, stream>>>(
            row, col, value, H1, S1, deg, nedges, 0);
        spmm16_kernel<<<(int)((thr1 + 255) / 256), 256, 0, stream>>>(
            row, col, value, S1, T, nullptr, nedges, 1);
        dense2_kernel<<<(n + 3) / 4, 256, 0, stream>>>(T, deg, W2, b2, out, n);
    }
}

// Round 3
// 513.866 us; speedup vs baseline: 1.2296x; 1.2296x over previous
//
#include <hip/hip_runtime.h>

#define IN_SIZE 256
#define HIDDEN 16
#define OUT_SIZE 64
#define SCAN_BLK 1024  // elements scanned per block (256 thr x 4)
#define EB 4096        // edges per bin block
#define NBUCK 256      // bucket slots (bucket = row >> 9, needs n <= 131072)

// ---------------- zero ----------------
__global__ __launch_bounds__(256) void zero_kernel(float* __restrict__ a, long n) {
    long i = (long)blockIdx.x * blockDim.x + threadIdx.x;
    long stride = (long)gridDim.x * blockDim.x;
    for (; i < n; i += stride) a[i] = 0.0f;
}

// ---------------- H1 = X @ W1^T + b1  [n,16] ----------------
__global__ __launch_bounds__(256) void dense1_kernel(
    const float* __restrict__ X, const float* __restrict__ W1,
    const float* __restrict__ b1, float* __restrict__ H1, int n) {
    __shared__ float w[HIDDEN * IN_SIZE];  // w[k*16 + h] = W1[h][k]
    for (int i = threadIdx.x; i < HIDDEN * IN_SIZE; i += 256) {
        int h = i >> 8;
        int k = i & 255;
        w[k * HIDDEN + h] = W1[i];
    }
    __syncthreads();
    int t = threadIdx.x;
    int node = blockIdx.x * 16 + (t >> 4);
    int h = t & 15;
    if (node >= n) return;
    const float4* xr = reinterpret_cast<const float4*>(X + (size_t)node * IN_SIZE);
    float acc = b1[h];
#pragma unroll 8
    for (int kk = 0; kk < IN_SIZE / 4; ++kk) {
        float4 x = xr[kk];
        const float* wr = &w[(kk * 4) * HIDDEN + h];
        acc += x.x * wr[0 * HIDDEN] + x.y * wr[1 * HIDDEN] +
               x.z * wr[2 * HIDDEN] + x.w * wr[3 * HIDDEN];
    }
    H1[(size_t)node * HIDDEN + h] = acc;
}

// ---------------- fused row-hist + bucket-hist ----------------
__global__ __launch_bounds__(256) void hist2_kernel(
    const int* __restrict__ row, int* __restrict__ cnt,
    int* __restrict__ bcnt, long nedges) {
    __shared__ int bh[NBUCK];
    for (int i = threadIdx.x; i < NBUCK; i += 256) bh[i] = 0;
    __syncthreads();
    long base = (long)blockIdx.x * EB;
    int ecount = (int)(((nedges - base) < (long)EB) ? (nedges - base) : (long)EB);
    for (int k = threadIdx.x; k < ecount; k += 256) {
        int r = row[base + k];
        atomicAdd(&cnt[r], 1);
        atomicAdd(&bh[r >> 9], 1);
    }
    __syncthreads();
    for (int i = threadIdx.x; i < NBUCK; i += 256)
        if (bh[i]) atomicAdd(&bcnt[i], bh[i]);
}

// ---------------- row_ptr scans ----------------
__global__ __launch_bounds__(256) void scan_blocks_kernel(
    const int* __restrict__ cnt, int* __restrict__ out, int* __restrict__ bsum, int n) {
    __shared__ int s[256];
    int base = blockIdx.x * SCAN_BLK;
    int tid = threadIdx.x;
    int v[4];
    int sum = 0;
#pragma unroll
    for (int j = 0; j < 4; ++j) {
        int i = base + tid * 4 + j;
        v[j] = (i < n) ? cnt[i] : 0;
        sum += v[j];
    }
    s[tid] = sum;
    __syncthreads();
    for (int off = 1; off < 256; off <<= 1) {
        int t = (tid >= off) ? s[tid - off] : 0;
        __syncthreads();
        s[tid] += t;
        __syncthreads();
    }
    int run = s[tid] - sum;
    if (tid == 255) bsum[blockIdx.x] = s[255];
#pragma unroll
    for (int j = 0; j < 4; ++j) {
        int i = base + tid * 4 + j;
        if (i < n) out[i] = run;
        run += v[j];
    }
}

__global__ __launch_bounds__(256) void scan_top_kernel(int* __restrict__ bsum, int nb) {
    __shared__ int s[256];
    int tid = threadIdx.x;
    int x = (tid < nb) ? bsum[tid] : 0;
    s[tid] = x;
    __syncthreads();
    for (int off = 1; off < 256; off <<= 1) {
        int t = (tid >= off) ? s[tid - off] : 0;
        __syncthreads();
        s[tid] += t;
        __syncthreads();
    }
    if (tid < nb) bsum[tid] = s[tid] - x;
}

__global__ __launch_bounds__(256) void scan_add_kernel(
    int* __restrict__ row_ptr, int* __restrict__ cursor,
    const int* __restrict__ bsum, int n, int nedges) {
    int i = blockIdx.x * 256 + threadIdx.x;
    if (i < n) {
        int v = row_ptr[i] + bsum[i / SCAN_BLK];
        row_ptr[i] = v;
        cursor[i] = v;
    }
    if (i == n) row_ptr[n] = nedges;
}

// ---------------- bucket scan: bcnt -> bcur (exclusive bases) ----------------
__global__ __launch_bounds__(256) void bucket_scan_kernel(
    const int* __restrict__ bcnt, int* __restrict__ bcur) {
    __shared__ int s[256];
    int tid = threadIdx.x;
    int x = bcnt[tid];
    s[tid] = x;
    __syncthreads();
    for (int off = 1; off < 256; off <<= 1) {
        int t = (tid >= off) ? s[tid - off] : 0;
        __syncthreads();
        s[tid] += t;
        __syncthreads();
    }
    bcur[tid] = s[tid] - x;
}

// ---------------- pass 1: bin edges by bucket (coalesced run writes) --------
__global__ __launch_bounds__(256) void bin_kernel(
    const int* __restrict__ row, const int* __restrict__ col,
    const float* __restrict__ val, int* __restrict__ bcur,
    int* __restrict__ bin, long nedges) {
    __shared__ int hist[NBUCK];
    __shared__ int cnt2[NBUCK];
    __shared__ int lbase[NBUCK];
    __shared__ int shiftd[NBUCK];
    __shared__ int scanbuf[NBUCK];
    __shared__ int staged[EB * 3];
    long base = (long)blockIdx.x * EB;
    int ecount = (int)(((nedges - base) < (long)EB) ? (nedges - base) : (long)EB);
    int tid = threadIdx.x;
    for (int i = tid; i < NBUCK; i += 256) { hist[i] = 0; cnt2[i] = 0; }
    __syncthreads();
    // pass A: count buckets
    for (int k = tid; k < ecount; k += 256)
        atomicAdd(&hist[row[base + k] >> 9], 1);
    __syncthreads();
    // scan hist -> lbase (exclusive), reserve global space per bucket
    {
        int x = hist[tid];
        scanbuf[tid] = x;
        __syncthreads();
        for (int off = 1; off < 256; off <<= 1) {
            int t = (tid >= off) ? scanbuf[tid - off] : 0;
            __syncthreads();
            scanbuf[tid] += t;
            __syncthreads();
        }
        int excl = scanbuf[tid] - x;
        lbase[tid] = excl;
        if (x > 0) {
            int g = atomicAdd(&bcur[tid], x);
            shiftd[tid] = 3 * (g - excl);
        }
    }
    __syncthreads();
    // pass B: place edges into LDS staged (bucket-major within block)
    for (int k = tid; k < ecount; k += 256) {
        long e = base + k;
        int r = row[e];
        int b = r >> 9;
        int p = lbase[b] + atomicAdd(&cnt2[b], 1);
        staged[3 * p]     = r;
        staged[3 * p + 1] = col[e];
        staged[3 * p + 2] = __float_as_int(val[e]);
    }
    __syncthreads();
    // pass C: copy LDS -> global, runs of ~21 edges per bucket are contiguous
    int nd = 3 * ecount;
    for (int j = tid; j < nd; j += 256) {
        int i = j / 3;
        int b = staged[3 * i] >> 9;
        bin[j + shiftd[b]] = staged[j];
    }
}

// ---------------- pass 2: place binned edges at exact CSR positions ---------
// bin is bucket-major, so cursor lines + epack destinations are L2-local.
__global__ __launch_bounds__(256) void place_kernel(
    const int* __restrict__ bin, int* __restrict__ cursor,
    float2* __restrict__ epack, long nedges) {
    long e = (long)blockIdx.x * 256 + threadIdx.x;
    if (e >= nedges) return;
    int r = bin[3 * e];
    int c = bin[3 * e + 1];
    int v = bin[3 * e + 2];
    int p = atomicAdd(&cursor[r], 1);
    epack[p] = make_float2(__int_as_float(c), __int_as_float(v));
}

// ---------------- legacy single-pass scatter (fallback) ----------------
__global__ __launch_bounds__(256) void scatter_kernel(
    const int* __restrict__ row, const int* __restrict__ col,
    const float* __restrict__ val, int* __restrict__ cursor,
    float2* __restrict__ epack, long nedges) {
    long e = (long)blockIdx.x * 256 + threadIdx.x;
    if (e >= nedges) return;
    int r = row[e];
    int p = atomicAdd(&cursor[r], 1);
    epack[p] = make_float2(__int_as_float(col[e]), val[e]);
}

// ---------------- pull spmm ----------------
__global__ __launch_bounds__(256) void spmm_pull_kernel(
    const int* __restrict__ row_ptr, const float2* __restrict__ epack,
    const float* __restrict__ Hin, float* __restrict__ Sout,
    float* __restrict__ deg, int n, int relu_in) {
    int t = blockIdx.x * 256 + threadIdx.x;
    int r = t >> 2;
    int q = t & 3;
    if (r >= n) return;
    int e0 = row_ptr[r], e1 = row_ptr[r + 1];
    float4 acc = make_float4(0.f, 0.f, 0.f, 0.f);
    float d = 0.f;
    for (int e = e0; e < e1; ++e) {
        float2 p = epack[e];
        int c = __float_as_int(p.x);
        float v = p.y;
        float4 x = reinterpret_cast<const float4*>(Hin + (size_t)c * HIDDEN)[q];
        if (relu_in) {
            x.x = fmaxf(x.x, 0.f); x.y = fmaxf(x.y, 0.f);
            x.z = fmaxf(x.z, 0.f); x.w = fmaxf(x.w, 0.f);
        }
        acc.x += v * x.x; acc.y += v * x.y;
        acc.z += v * x.z; acc.w += v * x.w;
        d += v;
    }
    reinterpret_cast<float4*>(Sout + (size_t)r * HIDDEN)[q] = acc;
    if (deg != nullptr && q == 0) deg[r] = d;
}

// ---------------- atomic push spmm (last-resort fallback) ----------------
__global__ __launch_bounds__(256) void spmm16_kernel(
    const int* __restrict__ row, const int* __restrict__ col,
    const float* __restrict__ val, const float* __restrict__ Hin,
    float* __restrict__ Sout, float* __restrict__ deg, long nedges, int relu_in) {
    long t = (long)blockIdx.x * 256 + threadIdx.x;
    long e = t >> 4;
    if (e >= nedges) return;
    int k = (int)(t & 15);
    int r = row[e];
    int c = col[e];
    float v = val[e];
    float x = Hin[(size_t)c * HIDDEN + k];
    if (relu_in) x = fmaxf(x, 0.0f);
    atomicAdd(&Sout[(size_t)r * HIDDEN + k], v * x);
    if (deg != nullptr && k == 0) atomicAdd(&deg[r], v);
}

// ---------------- out = relu(T @ W2^T + deg*b2)  [n,64] ----------------
__global__ __launch_bounds__(256) void dense2_kernel(
    const float* __restrict__ T, const float* __restrict__ deg,
    const float* __restrict__ W2, const float* __restrict__ b2,
    float* __restrict__ out, int n) {
    __shared__ float w[OUT_SIZE * HIDDEN];
    for (int i = threadIdx.x; i < OUT_SIZE * HIDDEN; i += 256) {
        int o = i / HIDDEN;
        int h = i % HIDDEN;
        w[h * OUT_SIZE + o] = W2[i];
    }
    __syncthreads();
    int node = blockIdx.x * 4 + (threadIdx.x >> 6);
    int o = threadIdx.x & 63;
    if (node >= n) return;
    float acc = deg[node] * b2[o];
#pragma unroll
    for (int h = 0; h < HIDDEN; ++h)
        acc += T[(size_t)node * HIDDEN + h] * w[h * OUT_SIZE + o];
    out[(size_t)node * OUT_SIZE + o] = fmaxf(acc, 0.0f);
}

static inline char* align_up(char* p, size_t a) {
    return (char*)(((uintptr_t)p + a - 1) & ~(uintptr_t)(a - 1));
}

extern "C" void kernel_launch(void* const* d_in, const int* in_sizes, int n_in,
                              void* d_out, int out_size, void* d_ws, size_t ws_size,
                              hipStream_t stream) {
    const int*   index = (const int*)d_in[0];
    const float* value = (const float*)d_in[1];
    const float* X     = (const float*)d_in[4];
    const float* W1    = (const float*)d_in[5];
    const float* b1    = (const float*)d_in[6];
    const float* W2    = (const float*)d_in[7];
    const float* b2    = (const float*)d_in[8];
    float* out = (float*)d_out;

    long nedges = in_sizes[1];
    int  n      = in_sizes[4] / IN_SIZE;
    const int* row = index;
    const int* col = index + nedges;

    int eblocks4k = (int)((nedges + EB - 1) / EB);
    int nb = (n + SCAN_BLK - 1) / SCAN_BLK;

    // ---- binned-CSR workspace layout ----
    size_t need_bin = (size_t)nedges * 8 + (size_t)nedges * 12 +
                      ((size_t)3 * n + 1 + 3 * 256) * 4 +
                      ((size_t)n * 2 * HIDDEN + n) * 4 + 512;
    size_t need_r2  = (size_t)nedges * 8 + ((size_t)3 * n + 1 + 256) * 4 +
                      ((size_t)n * 2 * HIDDEN + n) * 4 + 256;

    if (ws_size >= need_bin && n <= 131072 && nb <= 256) {
        char* p = (char*)d_ws;
        float2* epack = (float2*)p;            p += (size_t)nedges * 8;
        int* bin      = (int*)p;               p += (size_t)nedges * 12;
        int* cnt      = (int*)p;               p += (size_t)n * 4;
        int* row_ptr  = (int*)p;               p += (size_t)(n + 1) * 4;
        int* cursor   = (int*)p;               p += (size_t)n * 4;
        int* bsum     = (int*)p;               p += 256 * 4;
        int* bcnt     = (int*)p;               p += 256 * 4;
        int* bcur     = (int*)p;               p += 256 * 4;
        p = align_up(p, 64);
        float* H1     = (float*)p;             p += (size_t)n * HIDDEN * 4;
        float* S1     = (float*)p;             p += (size_t)n * HIDDEN * 4;
        float* deg    = (float*)p;

        // zero cnt[n] and bcnt lives after bsum; zero cnt..bcur region lazily:
        // cnt[n] then (row_ptr/cursor are fully overwritten), bcnt+bcur zeroed here.
        zero_kernel<<<256, 256, 0, stream>>>((float*)cnt, n);
        zero_kernel<<<1, 256, 0, stream>>>((float*)bcnt, 512);  // bcnt + bcur

        hist2_kernel<<<eblocks4k, 256, 0, stream>>>(row, cnt, bcnt, nedges);
        scan_blocks_kernel<<<nb, 256, 0, stream>>>(cnt, row_ptr, bsum, n);
        scan_top_kernel<<<1, 256, 0, stream>>>(bsum, nb);
        scan_add_kernel<<<(n + 256) / 256, 256, 0, stream>>>(row_ptr, cursor, bsum, n, (int)nedges);
        bucket_scan_kernel<<<1, 256, 0, stream>>>(bcnt, bcur);
        bin_kernel<<<eblocks4k, 256, 0, stream>>>(row, col, value, bcur, bin, nedges);
        place_kernel<<<(int)((nedges + 255) / 256), 256, 0, stream>>>(bin, cursor, epack, nedges);

        dense1_kernel<<<(n + 15) / 16, 256, 0, stream>>>(X, W1, b1, H1, n);

        int sblocks = ((n * 4) + 255) / 256;
        spmm_pull_kernel<<<sblocks, 256, 0, stream>>>(row_ptr, epack, H1, S1, deg, n, 0);
        float* T = H1;
        spmm_pull_kernel<<<sblocks, 256, 0, stream>>>(row_ptr, epack, S1, T, nullptr, n, 1);

        dense2_kernel<<<(n + 3) / 4, 256, 0, stream>>>(T, deg, W2, b2, out, n);
    } else if (ws_size >= need_r2) {
        // round-2 path: single-pass scatter CSR
        float2* epack  = (float2*)d_ws;
        int* cnt       = (int*)(epack + nedges);
        int* row_ptr   = cnt + n;
        int* cursor    = row_ptr + (n + 1);
        int* bsum      = cursor + n;
        char* p = align_up((char*)(bsum + 256), 64);
        float* H1      = (float*)p;
        float* S1      = H1 + (size_t)n * HIDDEN;
        float* deg     = S1 + (size_t)n * HIDDEN;

        int eblocks = (int)((nedges + 255) / 256);
        zero_kernel<<<256, 256, 0, stream>>>((float*)cnt, n);
        // reuse hist2 without bucket part via scatter-era hist: use hist2 with bcnt->bsum scratch? keep simple:
        hist2_kernel<<<eblocks4k, 256, 0, stream>>>(row, cnt, bsum, nedges);  // bsum clobbered, rewritten below
        scan_blocks_kernel<<<nb, 256, 0, stream>>>(cnt, row_ptr, bsum, n);
        scan_top_kernel<<<1, 256, 0, stream>>>(bsum, nb);
        scan_add_kernel<<<(n + 256) / 256, 256, 0, stream>>>(row_ptr, cursor, bsum, n, (int)nedges);
        scatter_kernel<<<eblocks, 256, 0, stream>>>(row, col, value, cursor, epack, nedges);

        dense1_kernel<<<(n + 15) / 16, 256, 0, stream>>>(X, W1, b1, H1, n);
        int sblocks = ((n * 4) + 255) / 256;
        spmm_pull_kernel<<<sblocks, 256, 0, stream>>>(row_ptr, epack, H1, S1, deg, n, 0);
        float* T = H1;
        spmm_pull_kernel<<<sblocks, 256, 0, stream>>>(row_ptr, epack, S1, T, nullptr, n, 1);
        dense2_kernel<<<(n + 3) / 4, 256, 0, stream>>>(T, deg, W2, b2, out, n);
    } else {
        // atomic push fallback
        float* ws = (float*)d_ws;
        float* H1  = ws;
        float* S1  = H1 + (size_t)n * HIDDEN;
        float* T   = S1 + (size_t)n * HIDDEN;
        float* deg = T + (size_t)n * HIDDEN;
        zero_kernel<<<2048, 256, 0, stream>>>(S1, (long)n * (2 * HIDDEN + 1));
        dense1_kernel<<<(n + 15) / 16, 256, 0, stream>>>(X, W1, b1, H1, n);
        long thr1 = nedges * HIDDEN;
        spmm16_kernel<<<(int)((thr1 + 255) / 256), 256, 0, stream>>>(
            row, col, value, H1, S1, deg, nedges, 0);
        spmm16_kernel<<<(int)((thr1 + 255) / 256), 256, 0, stream>>>(
            row, col, value, S1, T, nullptr, nedges, 1);
        dense2_kernel<<<(n + 3) / 4, 256, 0, stream>>>(T, deg, W2, b2, out, n);
    }
}